// Round 6
// baseline (719.150 us; speedup 1.0000x reference)
//
#include <hip/hip_runtime.h>
#include <stdint.h>

#define M_DIM 4096
#define K_DIM 4096
#define N_DIM 11008

typedef _Float16 half2v __attribute__((ext_vector_type(2)));
typedef _Float16 half8  __attribute__((ext_vector_type(8)));
typedef float    f32x16 __attribute__((ext_vector_type(16)));

#define SCHED_FENCE() __builtin_amdgcn_sched_barrier(0)

// cvt_pkrtz returns __fp16x2; route through bits (clang _Float16/__fp16 mismatch).
__device__ __forceinline__ unsigned int pkrtz_bits(float a, float b) {
  typedef __fp16 fp16x2 __attribute__((ext_vector_type(2)));
  union { fp16x2 h; unsigned int u; } c;
  c.h = __builtin_amdgcn_cvt_pkrtz(a, b);
  return c.u;
}

// Pack 8 f32 (exactly-fp16-valued) into fp16, Marlin order {0,4,1,5,2,6,3,7}.
__device__ __forceinline__ half8 pack8(float4 lo, float4 hi) {
  union { unsigned int u[4]; half8 v; } r;
  r.u[0] = pkrtz_bits(lo.x, hi.x);
  r.u[1] = pkrtz_bits(lo.y, hi.y);
  r.u[2] = pkrtz_bits(lo.z, hi.z);
  r.u[3] = pkrtz_bits(lo.w, hi.w);
  return r.v;
}

// Pre-pass: X f32 [M][K] -> fp16 [M][K], k-permuted within each octet.
__global__ __launch_bounds__(256) void convert_x(const float* __restrict__ X,
                                                 _Float16* __restrict__ X16) {
  size_t g = (size_t)blockIdx.x * 256 + threadIdx.x;
  const float4* p = (const float4*)(X + g * 8);
  float4 lo = p[0], hi = p[1];
  *(half8*)(X16 + g * 8) = pack8(lo, hi);
}

// 8 nibbles -> 8 fp16 (q - (z+1)), Marlin order; zoff = half2(1025+z,1025+z).
__device__ __forceinline__ half8 unpack8(unsigned int q, half2v zoff) {
  union { unsigned int u; half2v h; } t0, t1, t2, t3;
  t0.u = (q & 0x000F000Fu) | 0x64006400u;
  t1.u = ((q >> 4) & 0x000F000Fu) | 0x64006400u;
  t2.u = ((q >> 8) & 0x000F000Fu) | 0x64006400u;
  t3.u = ((q >> 12) & 0x000F000Fu) | 0x64006400u;
  union { half2v h[4]; half8 v; } r;
  r.h[0] = t0.h - zoff;
  r.h[1] = t1.h - zoff;
  r.h[2] = t2.h - zoff;
  r.h[3] = t3.h - zoff;
  return r.v;
}

// Async global->LDS, 16B/lane. LDS dst = wave-uniform base + lane*16 (m97 pattern).
__device__ __forceinline__ void stage16(const void* g, void* l) {
  __builtin_amdgcn_global_load_lds((__attribute__((address_space(1))) unsigned int*)g,
                                   (__attribute__((address_space(3))) unsigned int*)l,
                                   16, 0, 0);
}

// r5: combine the two HW-verified halves of rounds 0-5:
//  - 32x32x16 MFMA + 128-tall wave tile (r4: cut absolute VALU-busy 247->113us;
//    each B-unpack feeds 8 MFMA, A-frag reads per flop halved)
//  - multi-block occupancy + r2 loop mechanics (best measured 485us; 3-buffer,
//    2-stage-ahead prefetch, counted vmcnt -- cross-block overlap gave
//    MFMA+VALU issue ~85% vs 53% at 1 block/CU)
// Geometry: BM=256, BN=128, BK=32, 4 waves (2m x 2n), wave tile 128x64 =
// 4mt x 2nt x 16 MFMA/stage. LDS 3 x 16KB = 48KB; regs ~210/wave
// -> 2 waves/SIMD -> TWO independent blocks/CU (the r0/r2 overlap regime).
// Per stage 8 VMEM events (4 stage16 + 4 B loads); barrier waits vmcnt(8).
__global__ __launch_bounds__(256, 2) void gptq_gemm(
    const _Float16* __restrict__ X16,   // fp16 [M][K], Marlin octet order (d_ws)
    const int* __restrict__ QW,         // int32 [K/8][N]
    const int* __restrict__ QZ,         // int32 [1][N/8]
    const float* __restrict__ SC,       // f32 [1][N]
    float* __restrict__ OUT) {          // f32 [M][N]
  const int tid  = threadIdx.x;
  const int lane = tid & 63;
  const int wave = tid >> 6;      // 0..3
  const int wr   = wave >> 1;     // 0..1 (m row)
  const int wc   = wave & 1;      // 0..1 (n col)
  const int l32  = lane & 31;
  const int kh   = lane >> 5;     // 0..1 (k half of the MFMA fragment)
  const int bx = blockIdx.x;      // 86
  const int by = blockIdx.y;      // 16

  __shared__ __align__(16) _Float16 ldsA[3 * 8192];  // 3 x 16KB = 48 KB

  // Staging: thread t owns row m = t; chunk i = octet i of the stage's BK=32.
  // LDS chunk c = i*256 + t at f16 offset c*8 -> [octet:4][m:256] per buffer.
  const _Float16* gA = X16 + (size_t)(by * 256 + tid) * K_DIM;  // + ks*32 + i*8
  // B: fragment (stage ks, k-step s): QW row = ks*4 + s*2 + kh, col = n.
  const int* qB = QW + (size_t)kh * N_DIM + bx * 128 + wc * 64 + l32;

  half2v zoff[2];
  float sc[2];
#pragma unroll
  for (int nt = 0; nt < 2; ++nt) {
    int n = bx * 128 + wc * 64 + nt * 32 + l32;
    int z = (QZ[n >> 3] >> ((n & 7) * 4)) & 15;
    union { unsigned int u; half2v h; } zc;
    unsigned int zb = 0x6400u + (unsigned int)(z + 1);   // fp16 bits of 1025+z
    zc.u = (zb << 16) | zb;
    zoff[nt] = zc.h;
    sc[nt] = SC[n];
  }

  f32x16 acc[4][2] = {};
  int q0[2][2], q1[2][2];

  // ---- Prologue: stage 0 -> buf0/q0; stage 1 -> buf1/q1 (8 VMEM each).
  {
    _Float16* lb = ldsA + (size_t)tid * 8;
#pragma unroll
    for (int i = 0; i < 4; ++i)
      stage16(gA + i * 8, lb + i * 2048);
#pragma unroll
    for (int s = 0; s < 2; ++s)
#pragma unroll
      for (int nt = 0; nt < 2; ++nt)
        q0[s][nt] = qB[(size_t)(s * 2) * N_DIM + nt * 32];
    SCHED_FENCE();
#pragma unroll
    for (int i = 0; i < 4; ++i)
      stage16(gA + 32 + i * 8, lb + 8192 + i * 2048);
#pragma unroll
    for (int s = 0; s < 2; ++s)
#pragma unroll
      for (int nt = 0; nt < 2; ++nt)
        q1[s][nt] = qB[(size_t)(4 + s * 2) * N_DIM + nt * 32];
    SCHED_FENCE();
  }
  gA += 32;                 // so loop-top advance yields stage ks+2
  qB += (size_t)4 * N_DIM;
  asm volatile("s_waitcnt vmcnt(8)" ::: "memory");  // stage-0's 8 drained
  __builtin_amdgcn_s_barrier();

  int rb = 0;  // buffer read this stage  (ks % 3)
  int wb = 2;  // buffer written this stage ((ks+2) % 3)
  for (int ks = 0; ks < 128; ++ks) {
    // Issue stage ks+2's A-staging + B prefetch FIRST (8 VMEM events).
    int nq[2][2];
    if (ks < 126) {
      gA += 32;
      qB += (size_t)4 * N_DIM;
      _Float16* lb = ldsA + wb * 8192 + (size_t)tid * 8;
#pragma unroll
      for (int i = 0; i < 4; ++i)
        stage16(gA + i * 8, lb + i * 2048);
#pragma unroll
      for (int s = 0; s < 2; ++s)
#pragma unroll
        for (int nt = 0; nt < 2; ++nt)
          nq[s][nt] = qB[(size_t)(s * 2) * N_DIM + nt * 32];
      SCHED_FENCE();
    }

    // Compute current stage from buf rb (2 K=16 steps), B from q0.
    const _Float16* base = ldsA + rb * 8192;
#pragma unroll
    for (int s = 0; s < 2; ++s) {
      const _Float16* ab = base + (size_t)((s * 2 + kh) * 256 + wr * 128 + l32) * 8;
      half8 a0 = *(const half8*)(ab);
      half8 a1 = *(const half8*)(ab + 32 * 8);
      half8 a2 = *(const half8*)(ab + 64 * 8);
      half8 a3 = *(const half8*)(ab + 96 * 8);
      half8 b0 = unpack8((unsigned int)q0[s][0], zoff[0]);
      half8 b1 = unpack8((unsigned int)q0[s][1], zoff[1]);
      __builtin_amdgcn_s_setprio(1);
      acc[0][0] = __builtin_amdgcn_mfma_f32_32x32x16_f16(a0, b0, acc[0][0], 0, 0, 0);
      acc[0][1] = __builtin_amdgcn_mfma_f32_32x32x16_f16(a0, b1, acc[0][1], 0, 0, 0);
      acc[1][0] = __builtin_amdgcn_mfma_f32_32x32x16_f16(a1, b0, acc[1][0], 0, 0, 0);
      acc[1][1] = __builtin_amdgcn_mfma_f32_32x32x16_f16(a1, b1, acc[1][1], 0, 0, 0);
      acc[2][0] = __builtin_amdgcn_mfma_f32_32x32x16_f16(a2, b0, acc[2][0], 0, 0, 0);
      acc[2][1] = __builtin_amdgcn_mfma_f32_32x32x16_f16(a2, b1, acc[2][1], 0, 0, 0);
      acc[3][0] = __builtin_amdgcn_mfma_f32_32x32x16_f16(a3, b0, acc[3][0], 0, 0, 0);
      acc[3][1] = __builtin_amdgcn_mfma_f32_32x32x16_f16(a3, b1, acc[3][1], 0, 0, 0);
      __builtin_amdgcn_s_setprio(0);
    }

    // Rotate B prefetch registers and buffer indices.
#pragma unroll
    for (int s = 0; s < 2; ++s)
#pragma unroll
      for (int nt = 0; nt < 2; ++nt) {
        q0[s][nt] = q1[s][nt];
        if (ks < 126) q1[s][nt] = nq[s][nt];
      }
    rb = (rb == 2) ? 0 : rb + 1;
    wb = (wb == 2) ? 0 : wb + 1;

    // Counted-vmcnt barrier: drain the PREVIOUS stage's 8 (next buf ready),
    // keep this stage's 8 in flight. Full drain only at the tail.
    if (ks < 127) {
      SCHED_FENCE();
      if (ks < 126)
        asm volatile("s_waitcnt vmcnt(8)" ::: "memory");
      else
        asm volatile("s_waitcnt vmcnt(0)" ::: "memory");
      __builtin_amdgcn_s_barrier();
    }
  }

  // Epilogue: 32x32 C/D layout (m74/m101, HW-verified in r4): col=lane&31,
  // row=(reg&3)+8*(reg>>2)+4*(lane>>5).
#pragma unroll
  for (int mt = 0; mt < 4; ++mt) {
#pragma unroll
    for (int nt = 0; nt < 2; ++nt) {
      const int n = bx * 128 + wc * 64 + nt * 32 + l32;
      const float s = sc[nt];
      const size_t mb = (size_t)(by * 256 + wr * 128 + mt * 32 + kh * 4);
#pragma unroll
      for (int r = 0; r < 16; ++r) {
        const int row = (r & 3) + 8 * (r >> 2);
        OUT[(mb + row) * N_DIM + n] = acc[mt][nt][r] * s;
      }
    }
  }
}

extern "C" void kernel_launch(void* const* d_in, const int* in_sizes, int n_in,
                              void* d_out, int out_size, void* d_ws, size_t ws_size,
                              hipStream_t stream) {
  const float* X  = (const float*)d_in[0];
  const int* QW   = (const int*)d_in[1];
  const int* QZ   = (const int*)d_in[2];
  const float* SC = (const float*)d_in[3];
  float* OUT      = (float*)d_out;
  _Float16* X16   = (_Float16*)d_ws;   // 32 MiB

  convert_x<<<dim3((M_DIM * (size_t)K_DIM / 8) / 256), 256, 0, stream>>>(X, X16);
  dim3 grid(N_DIM / 128, M_DIM / 256);
  gptq_gemm<<<grid, 256, 0, stream>>>(X16, QW, QZ, SC, OUT);
}

// Round 7
// 666.337 us; speedup vs baseline: 1.0793x; 1.0793x over previous
//
#include <hip/hip_runtime.h>
#include <stdint.h>

#define M_DIM 4096
#define K_DIM 4096
#define N_DIM 11008

typedef _Float16 half2v __attribute__((ext_vector_type(2)));
typedef _Float16 half8  __attribute__((ext_vector_type(8)));
typedef float    f32x16 __attribute__((ext_vector_type(16)));

#define SCHED_FENCE() __builtin_amdgcn_sched_barrier(0)

// cvt_pkrtz returns __fp16x2; route through bits (clang _Float16/__fp16 mismatch).
__device__ __forceinline__ unsigned int pkrtz_bits(float a, float b) {
  typedef __fp16 fp16x2 __attribute__((ext_vector_type(2)));
  union { fp16x2 h; unsigned int u; } c;
  c.h = __builtin_amdgcn_cvt_pkrtz(a, b);
  return c.u;
}

// Pack 8 f32 (exactly-fp16-valued) into fp16, Marlin order {0,4,1,5,2,6,3,7}.
__device__ __forceinline__ half8 pack8(float4 lo, float4 hi) {
  union { unsigned int u[4]; half8 v; } r;
  r.u[0] = pkrtz_bits(lo.x, hi.x);
  r.u[1] = pkrtz_bits(lo.y, hi.y);
  r.u[2] = pkrtz_bits(lo.z, hi.z);
  r.u[3] = pkrtz_bits(lo.w, hi.w);
  return r.v;
}

// Pre-pass: X f32 [M][K] -> fp16 [M][K], k-permuted within each octet.
__global__ __launch_bounds__(256) void convert_x(const float* __restrict__ X,
                                                 _Float16* __restrict__ X16) {
  size_t g = (size_t)blockIdx.x * 256 + threadIdx.x;
  const float4* p = (const float4*)(X + g * 8);
  float4 lo = p[0], hi = p[1];
  *(half8*)(X16 + g * 8) = pack8(lo, hi);
}

// 8 nibbles -> 8 fp16 (q - (z+1)), Marlin order; zoff = half2(1025+z,1025+z).
__device__ __forceinline__ half8 unpack8(unsigned int q, half2v zoff) {
  union { unsigned int u; half2v h; } t0, t1, t2, t3;
  t0.u = (q & 0x000F000Fu) | 0x64006400u;
  t1.u = ((q >> 4) & 0x000F000Fu) | 0x64006400u;
  t2.u = ((q >> 8) & 0x000F000Fu) | 0x64006400u;
  t3.u = ((q >> 12) & 0x000F000Fu) | 0x64006400u;
  union { half2v h[4]; half8 v; } r;
  r.h[0] = t0.h - zoff;
  r.h[1] = t1.h - zoff;
  r.h[2] = t2.h - zoff;
  r.h[3] = t3.h - zoff;
  return r.v;
}

// Async global->LDS, 16B/lane. LDS dst = wave-uniform base + lane*16 (m97 pattern).
__device__ __forceinline__ void stage16(const void* g, void* l) {
  __builtin_amdgcn_global_load_lds((__attribute__((address_space(1))) unsigned int*)g,
                                   (__attribute__((address_space(3))) unsigned int*)l,
                                   16, 0, 0);
}

// r6: r2's EXACT loop structure (best measured: 485us, 85% issue-sum, 3
// blocks/CU) with ONE change: MFMA shape 16x16x32 -> 32x32x16 inside the same
// 128x128/BK=64 tile. Evidence: r2 proved 3-blocks/CU cross-block overlap is
// what saturates issue (85% vs 52% at 1-2 blocks); r5 proved 32x32x16 halves
// absolute VALU-busy (133us vs 247us). This combines both at UNCHANGED
// occupancy: 4 waves 2x2, wave tile 64x64 = 2mt x 2nt, 4 K=16 steps -> 16
// MFMA 32x32x16/stage (512 matrix-cyc) vs 8 unpacks + 8 ds_read_b128
// (~150 VALU-cyc): issue mix flips from 40:60 to ~75:25. acc = 2x2x16 = 64
// AGPR (same as r2's 64), ~130 regs total -> 3 waves/SIMD preserved.
// Triple-buffer 3x16KB, 2-stage-ahead prefetch, 12 VMEM/stage, vmcnt(12),
// rotation (r3 disproved the rotation-stall theory: static slots were WORSE).
__global__ __launch_bounds__(256, 3) void gptq_gemm(
    const _Float16* __restrict__ X16,   // fp16 [M][K], Marlin octet order (d_ws)
    const int* __restrict__ QW,         // int32 [K/8][N]
    const int* __restrict__ QZ,         // int32 [1][N/8]
    const float* __restrict__ SC,       // f32 [1][N]
    float* __restrict__ OUT) {          // f32 [M][N]
  const int tid  = threadIdx.x;
  const int lane = tid & 63;
  const int wave = tid >> 6;      // 0..3
  const int wr   = wave >> 1;     // 0..1 (m row)
  const int wc   = wave & 1;      // 0..1 (n col)
  const int l32  = lane & 31;
  const int kh   = lane >> 5;     // 0..1 (k half of the MFMA fragment)
  const int bx = blockIdx.x;      // 86
  const int by = blockIdx.y;      // 32

  __shared__ __align__(16) _Float16 ldsA[3 * 1024 * 8];  // 48 KB, 3 buffers

  // Staging (identical to r2): thread t stages chunks c_i = i*256+t (i=0..3);
  // octet = c>>7, m = c&127 -> LDS [octet:8][m:128] per buffer.
  const _Float16* gA = X16 + (size_t)(by * 128 + (tid & 127)) * K_DIM + (tid >> 7) * 8;
  _Float16* lw = ldsA + (size_t)tid * 8;

  // B: frag (stage ks, k-step s): QW row = ks*8 + s*2 + kh; col = n.
  const int* qB = QW + (size_t)kh * N_DIM + bx * 128 + wc * 64 + l32;

  half2v zoff[2];
  float sc[2];
#pragma unroll
  for (int nt = 0; nt < 2; ++nt) {
    int n = bx * 128 + wc * 64 + nt * 32 + l32;
    int z = (QZ[n >> 3] >> ((n & 7) * 4)) & 15;
    union { unsigned int u; half2v h; } zc;
    unsigned int zb = 0x6400u + (unsigned int)(z + 1);   // fp16 bits of 1025+z
    zc.u = (zb << 16) | zb;
    zoff[nt] = zc.h;
    sc[nt] = SC[n];
  }

  f32x16 acc[2][2] = {};
  int q0[4][2], q1[4][2];

  // ---- Prologue: stage 0 -> buf0/q0; stage 1 -> buf1/q1 (12 VMEM each).
#pragma unroll
  for (int i = 0; i < 4; ++i)
    stage16(gA + i * 16, lw + i * 2048);
#pragma unroll
  for (int s = 0; s < 4; ++s)
#pragma unroll
    for (int nt = 0; nt < 2; ++nt)
      q0[s][nt] = qB[(size_t)(s * 2) * N_DIM + nt * 32];
  SCHED_FENCE();
  gA += 64;
  qB += (size_t)8 * N_DIM;
#pragma unroll
  for (int i = 0; i < 4; ++i)
    stage16(gA + i * 16, lw + 8192 + i * 2048);
#pragma unroll
  for (int s = 0; s < 4; ++s)
#pragma unroll
    for (int nt = 0; nt < 2; ++nt)
      q1[s][nt] = qB[(size_t)(s * 2) * N_DIM + nt * 32];
  SCHED_FENCE();
  // Drain stage-0's 12 (A0 + q0 ready); leave stage-1's 12 in flight.
  asm volatile("s_waitcnt vmcnt(12)" ::: "memory");
  __builtin_amdgcn_s_barrier();

  int rb = 0;  // buffer read this stage (= ks % 3)
  int wb = 2;  // buffer written this stage (= (ks+2) % 3)
  for (int ks = 0; ks < 64; ++ks) {
    // Issue stage ks+2's A-staging + B prefetch FIRST (12 VMEM events).
    int nq[4][2];
    if (ks < 62) {
      gA += 64;
      qB += (size_t)8 * N_DIM;
      _Float16* lb = ldsA + wb * 8192 + (size_t)tid * 8;
#pragma unroll
      for (int i = 0; i < 4; ++i)
        stage16(gA + i * 16, lb + i * 2048);
#pragma unroll
      for (int s = 0; s < 4; ++s)
#pragma unroll
        for (int nt = 0; nt < 2; ++nt)
          nq[s][nt] = qB[(size_t)(s * 2) * N_DIM + nt * 32];
      SCHED_FENCE();   // pin: all 12 issued before compute & before the vmcnt
    }

    // Compute current stage from buf rb: 4 K=16 steps, octet = s*2 + kh.
    const _Float16* base = ldsA + rb * 8192;
#pragma unroll
    for (int s = 0; s < 4; ++s) {
      const _Float16* ab = base + (size_t)((s * 2 + kh) * 128 + wr * 64 + l32) * 8;
      half8 a0 = *(const half8*)(ab);
      half8 a1 = *(const half8*)(ab + 32 * 8);
      half8 b0 = unpack8((unsigned int)q0[s][0], zoff[0]);
      half8 b1 = unpack8((unsigned int)q0[s][1], zoff[1]);
      __builtin_amdgcn_s_setprio(1);
      acc[0][0] = __builtin_amdgcn_mfma_f32_32x32x16_f16(a0, b0, acc[0][0], 0, 0, 0);
      acc[0][1] = __builtin_amdgcn_mfma_f32_32x32x16_f16(a0, b1, acc[0][1], 0, 0, 0);
      acc[1][0] = __builtin_amdgcn_mfma_f32_32x32x16_f16(a1, b0, acc[1][0], 0, 0, 0);
      acc[1][1] = __builtin_amdgcn_mfma_f32_32x32x16_f16(a1, b1, acc[1][1], 0, 0, 0);
      __builtin_amdgcn_s_setprio(0);
    }

    // Rotate B prefetch registers and buffer indices (r2-proven).
#pragma unroll
    for (int s = 0; s < 4; ++s)
#pragma unroll
      for (int nt = 0; nt < 2; ++nt) {
        q0[s][nt] = q1[s][nt];
        if (ks < 62) q1[s][nt] = nq[s][nt];
      }
    rb = (rb == 2) ? 0 : rb + 1;
    wb = (wb == 2) ? 0 : wb + 1;

    // Counted-vmcnt barrier: drain previous stage's 12 (next buf ready),
    // keep this stage's 12 in flight. Full drain only at the tail.
    if (ks < 63) {
      SCHED_FENCE();
      if (ks < 62)
        asm volatile("s_waitcnt vmcnt(12)" ::: "memory");
      else
        asm volatile("s_waitcnt vmcnt(0)" ::: "memory");
      __builtin_amdgcn_s_barrier();
    }
  }

  // Epilogue: 32x32 C/D layout (m74/m101, HW-verified r4/r5): col=lane&31,
  // row=(reg&3)+8*(reg>>2)+4*(lane>>5).
#pragma unroll
  for (int mt = 0; mt < 2; ++mt) {
#pragma unroll
    for (int nt = 0; nt < 2; ++nt) {
      const int n = bx * 128 + wc * 64 + nt * 32 + l32;
      const float s = sc[nt];
      const size_t mb = (size_t)(by * 128 + wr * 64 + mt * 32 + kh * 4);
#pragma unroll
      for (int r = 0; r < 16; ++r) {
        const int row = (r & 3) + 8 * (r >> 2);
        OUT[(mb + row) * N_DIM + n] = acc[mt][nt][r] * s;
      }
    }
  }
}

extern "C" void kernel_launch(void* const* d_in, const int* in_sizes, int n_in,
                              void* d_out, int out_size, void* d_ws, size_t ws_size,
                              hipStream_t stream) {
  const float* X  = (const float*)d_in[0];
  const int* QW   = (const int*)d_in[1];
  const int* QZ   = (const int*)d_in[2];
  const float* SC = (const float*)d_in[3];
  float* OUT      = (float*)d_out;
  _Float16* X16   = (_Float16*)d_ws;   // 32 MiB

  convert_x<<<dim3((M_DIM * (size_t)K_DIM / 8) / 256), 256, 0, stream>>>(X, X16);
  dim3 grid(N_DIM / 128, M_DIM / 128);
  gptq_gemm<<<grid, 256, 0, stream>>>(X16, QW, QZ, SC, OUT);
}